// Round 6
// baseline (226.409 us; speedup 1.0000x reference)
//
#include <hip/hip_runtime.h>

// B=4096 rows, F=128 features, A=8 heads, U=10 units (padded to 16).
// y = softmax_f( BN( (1/F) sum_{j,a,u} softmax_u(Z[j,a,b,:])[u] exp(2K[j,a,f,u]) fc_w[a] + fc_b ) )
// Z[j,a,b,u] = sum_f x[b,f] K[j,a,f,u] - x[b,j] K[j,a,j,u]
//
// MFMA plan (16x16x32 bf16, fp32 accum):
//   GEMM1 (transposed): Z^T[u][b] = KbT[u][f] * x[f][b]  -> u lives in-lane for softmax
//   GEMM2: acc[b][f] += P[b][k=(a-pair,u)] * W2[k][f], k=32 packs 2 heads per MFMA
// Grid: 64 b-tiles x NJ j-chunks; NJ chosen at runtime (16 if ws allows, else 8).

typedef __attribute__((ext_vector_type(8))) short short8v;
typedef __attribute__((ext_vector_type(4))) float f32x4;

__device__ inline unsigned short f2bf(float f) {
    union { float f; unsigned u; } c; c.f = f;
    return (unsigned short)((c.u + 0x7FFFu + ((c.u >> 16) & 1u)) >> 16);
}
__device__ inline float bf2f(unsigned short h) {
    union { unsigned u; float f; } c; c.u = ((unsigned)h) << 16;
    return c.f;
}

// ---------------------------------------------------------------------------
// Prep (coalesced): block = (j, pair p). Computes
//   KbT[j][a][u16][f128] bf16, W2[j][p][f128][k32] bf16 (k=ai*16+u), Kjj[j][a][u16].
// W2 tile staged in LDS [f][k] then written out dword-coalesced.
// ---------------------------------------------------------------------------
__global__ __launch_bounds__(256) void ife_prep3(
    const float* __restrict__ K, const float* __restrict__ fc_w,
    unsigned short* __restrict__ KbT, unsigned short* __restrict__ W2,
    unsigned short* __restrict__ Kjj) {
    const int j = blockIdx.x >> 2, p = blockIdx.x & 3;
    const int t = threadIdx.x;
    __shared__ unsigned short wt[128 * 32];      // [f][k]  8KB
    __shared__ unsigned short kt[2 * 128 * 16];  // [ai][f][u]  8KB
    const int ai = t >> 7, f = t & 127, a = p * 2 + ai;
    const float* src = K + (size_t)((j * 8 + a) * 128 + f) * 10;
    const float wscale = fc_w[a] * (1.0f / 128.0f);
    float kv[10];
#pragma unroll
    for (int u = 0; u < 10; ++u) kv[u] = src[u];
#pragma unroll
    for (int u = 0; u < 16; ++u) {
        unsigned short kb = (u < 10) ? f2bf(kv[u]) : (unsigned short)0;
        kt[(ai * 128 + f) * 16 + u] = kb;
        wt[f * 32 + ai * 16 + u] =
            (u < 10) ? f2bf(__expf(2.0f * kv[u]) * wscale) : (unsigned short)0;
        if (f == j) Kjj[(size_t)(j * 8 + a) * 16 + u] = kb;
    }
    __syncthreads();
    // W2 tile out: 2048 dwords, fully coalesced
    {
        const unsigned* s = (const unsigned*)wt;
        unsigned* d = (unsigned*)(W2 + (size_t)(j * 4 + p) * 128 * 32);
#pragma unroll
        for (int i = 0; i < 8; ++i) d[i * 256 + t] = s[i * 256 + t];
    }
    // KbT out for both heads: per head 1024 dwords, coalesced (transpose from kt)
#pragma unroll
    for (int a2 = 0; a2 < 2; ++a2) {
        unsigned* d = (unsigned*)(KbT + (size_t)((j * 8 + p * 2 + a2) * 16) * 128);
#pragma unroll
        for (int i = 0; i < 4; ++i) {
            int dd = i * 256 + t;
            int u = dd >> 6, f2 = (dd & 63) * 2;
            unsigned lo = kt[(a2 * 128 + f2) * 16 + u];
            unsigned hi = kt[(a2 * 128 + f2 + 1) * 16 + u];
            d[dd] = lo | (hi << 16);
        }
    }
}

// ---------------------------------------------------------------------------
// Main: block = 256 threads (4 waves), 64-row b-tile, one j-chunk (jpc j's).
// Wave w: GEMM1+softmax for heads a=2w,2w+1 (pair w); GEMM2 f-block w*32.
// ---------------------------------------------------------------------------
__global__ __launch_bounds__(256, 4) void ife_main2(
    const float* __restrict__ x, const unsigned short* __restrict__ KbT,
    const unsigned short* __restrict__ W2, const unsigned short* __restrict__ Kjj,
    float* __restrict__ yp, int jpc) {
    __shared__ unsigned xb[64 * 64];    // x tile bf16x2, f-octet XOR-swizzled (16KB)
    __shared__ unsigned pb[4 * 64 * 16];// P bf16x2 [pair][b][k-dword], swizzled (16KB)

    const int t = threadIdx.x;
    const int btile = blockIdx.x & 63;
    const int chunk = blockIdx.x >> 6;
    const int b0 = btile * 64;
    const int lane = t & 63;
    const int wv = __builtin_amdgcn_readfirstlane(t >> 6);
    const int lr = lane & 15;   // row/col within a 16-tile
    const int lg = lane >> 4;   // k-octet group (0..3)

    // stage x -> bf16 LDS: dword dw holds f=2dw,2dw+1; octet g stored at g^(b&7)
    for (int i = t; i < 64 * 64; i += 256) {
        int b = i >> 6, dw = i & 63;
        float2 v = *reinterpret_cast<const float2*>(x + (size_t)(b0 + b) * 128 + dw * 2);
        unsigned pk = (unsigned)f2bf(v.x) | ((unsigned)f2bf(v.y) << 16);
        int g = dw >> 2;
        xb[b * 64 + (((g ^ (b & 7)) << 2) | (dw & 3))] = pk;
    }
    __syncthreads();

    // x B-fragments, j- and a-invariant: held for the whole block.
    // frag(ks,nt): col b = nt*16+lr, k(f) = ks*32 + lg*8 .. +8
    short8v xf[16];
#pragma unroll
    for (int ks = 0; ks < 4; ++ks)
#pragma unroll
        for (int nt = 0; nt < 4; ++nt) {
            int b = nt * 16 + lr;
            int g = ks * 4 + lg;
            xf[ks * 4 + nt] = *reinterpret_cast<const short8v*>(
                &xb[b * 64 + ((g ^ (b & 7)) << 2)]);
        }

    f32x4 acc[4][2];
#pragma unroll
    for (int mt = 0; mt < 4; ++mt)
#pragma unroll
        for (int nt = 0; nt < 2; ++nt) acc[mt][nt] = f32x4{0.f, 0.f, 0.f, 0.f};

    const int ub = lg * 4;      // this lane's base u (GEMM1 D rows)

#pragma unroll 1
    for (int jj = 0; jj < jpc; ++jj) {
        const int j = chunk * jpc + jj;
        // ---------- GEMM1 + softmax + P-write for this wave's 2 heads ----------
#pragma unroll
        for (int ai = 0; ai < 2; ++ai) {
            const int a = wv * 2 + ai;
            const size_t kbase = (size_t)(j * 8 + a) * 16;
            short8v af[4];   // A-frag: row u=lr, k(f)=ks*32+lg*8
#pragma unroll
            for (int ks = 0; ks < 4; ++ks)
                af[ks] = *reinterpret_cast<const short8v*>(
                    KbT + (kbase + lr) * 128 + ks * 32 + lg * 8);
            f32x4 z[4];
#pragma unroll
            for (int nt = 0; nt < 4; ++nt) z[nt] = f32x4{0.f, 0.f, 0.f, 0.f};
#pragma unroll
            for (int ks = 0; ks < 4; ++ks)
#pragma unroll
                for (int nt = 0; nt < 4; ++nt)
                    z[nt] = __builtin_amdgcn_mfma_f32_16x16x32_bf16(
                        af[ks], xf[ks * 4 + nt], z[nt], 0, 0, 0);
            // rank-1 correction: z[u][b] -= K[j,a,j,u] * x[b,j]
            unsigned short kj0, kj1, kj2, kj3;
            {
                const unsigned short* kp = Kjj + kbase + ub;
                kj0 = kp[0]; kj1 = kp[1]; kj2 = kp[2]; kj3 = kp[3];
            }
            const int gj = j >> 3;
#pragma unroll
            for (int nt = 0; nt < 4; ++nt) {
                int b = nt * 16 + lr;
                unsigned pkx = xb[b * 64 + (((gj ^ (b & 7)) << 2) | ((j >> 1) & 3))];
                float xbj = bf2f((unsigned short)((j & 1) ? (pkx >> 16) : (pkx & 0xFFFFu)));
                z[nt][0] = fmaf(-bf2f(kj0), xbj, z[nt][0]);
                z[nt][1] = fmaf(-bf2f(kj1), xbj, z[nt][1]);
                z[nt][2] = fmaf(-bf2f(kj2), xbj, z[nt][2]);
                z[nt][3] = fmaf(-bf2f(kj3), xbj, z[nt][3]);
            }
            // softmax over u (in-lane 4 + shfl_xor 16/32), mask u>=10, pack to pb
#pragma unroll
            for (int nt = 0; nt < 4; ++nt) {
                float m = -3.0e38f;
#pragma unroll
                for (int q = 0; q < 4; ++q)
                    m = (ub + q < 10) ? fmaxf(m, z[nt][q]) : m;
                m = fmaxf(m, __shfl_xor(m, 16, 64));
                m = fmaxf(m, __shfl_xor(m, 32, 64));
                float e0 = (ub + 0 < 10) ? __expf(z[nt][0] - m) : 0.f;
                float e1 = (ub + 1 < 10) ? __expf(z[nt][1] - m) : 0.f;
                float e2 = (ub + 2 < 10) ? __expf(z[nt][2] - m) : 0.f;
                float e3 = (ub + 3 < 10) ? __expf(z[nt][3] - m) : 0.f;
                float s = e0 + e1 + e2 + e3;
                s += __shfl_xor(s, 16, 64);
                s += __shfl_xor(s, 32, 64);
                float inv = 1.0f / s;
                int b = nt * 16 + lr;
                unsigned pk0 = (unsigned)f2bf(e0 * inv) | ((unsigned)f2bf(e1 * inv) << 16);
                unsigned pk1 = (unsigned)f2bf(e2 * inv) | ((unsigned)f2bf(e3 * inv) << 16);
                int dw0 = ai * 8 + lg * 2;           // k-dword col (k = ai*16 + u)
                int base = (wv * 64 + b) * 16;
                int swz = (b >> 1) & 3;
                pb[base + ((((dw0 >> 2) ^ swz) << 2) | (dw0 & 3))] = pk0;
                pb[base + ((((dw0 + 1) >> 2) ^ swz) << 2) + ((dw0 + 1) & 3)] = pk1;
            }
        }
        __syncthreads();
        // ---------- GEMM2: acc[b][f-block wv*32] += P * W2 ----------
#pragma unroll
        for (int p = 0; p < 4; ++p) {
            short8v wf[2];   // B-frag: col f = wv*32+nt*16+lr, k = lg*8..+8
#pragma unroll
            for (int nt = 0; nt < 2; ++nt) {
                int f = wv * 32 + nt * 16 + lr;
                wf[nt] = *reinterpret_cast<const short8v*>(
                    W2 + (((size_t)(j * 4 + p) * 128 + f) * 32) + lg * 8);
            }
#pragma unroll
            for (int mt = 0; mt < 4; ++mt) {
                int b = mt * 16 + lr;
                short8v pf = *reinterpret_cast<const short8v*>(
                    &pb[(p * 64 + b) * 16 + ((lg ^ ((b >> 1) & 3)) << 2)]);
#pragma unroll
                for (int nt = 0; nt < 2; ++nt)
                    acc[mt][nt] = __builtin_amdgcn_mfma_f32_16x16x32_bf16(
                        pf, wf[nt], acc[mt][nt], 0, 0, 0);
            }
        }
        __syncthreads();
    }
    // store partials: D layout col=lr (f), row=lg*4+q (b)
    float* ypb = yp + ((size_t)chunk * 4096 + b0) * 128;
#pragma unroll
    for (int mt = 0; mt < 4; ++mt)
#pragma unroll
        for (int nt = 0; nt < 2; ++nt) {
            int f = wv * 32 + nt * 16 + lr;
#pragma unroll
            for (int q = 0; q < 4; ++q) {
                int b = mt * 16 + lg * 4 + q;
                ypb[(size_t)b * 128 + f] = acc[mt][nt][q];
            }
        }
}

// ---------------------------------------------------------------------------
// Finalize: sum nj partials, + fc_b, inference BN, row-softmax over F=128.
// ---------------------------------------------------------------------------
__global__ void ife_final(const float* __restrict__ yp, const float* __restrict__ fc_b,
                          const float* __restrict__ gamma, const float* __restrict__ beta,
                          const float* __restrict__ mmean, const float* __restrict__ mvar,
                          float* __restrict__ out, int nj) {
    const int b = blockIdx.x;
    const int f = threadIdx.x;  // 128
    float s = 0.f;
#pragma unroll 1
    for (int n = 0; n < nj; ++n)
        s += yp[((size_t)n * 4096 + b) * 128 + f];
    const float scale = gamma[0] * rsqrtf(mvar[0] + 1e-3f);
    float y = (s + fc_b[0] - mmean[0]) * scale + beta[0];

    __shared__ float redm[2], reds[2];
    float m = y;
#pragma unroll
    for (int o = 32; o >= 1; o >>= 1) m = fmaxf(m, __shfl_xor(m, o, 64));
    const int wid = f >> 6;
    if ((f & 63) == 0) redm[wid] = m;
    __syncthreads();
    m = fmaxf(redm[0], redm[1]);
    float e = __expf(y - m);
    float ss = e;
#pragma unroll
    for (int o = 32; o >= 1; o >>= 1) ss += __shfl_xor(ss, o, 64);
    if ((f & 63) == 0) reds[wid] = ss;
    __syncthreads();
    out[(size_t)b * 128 + f] = e / (reds[0] + reds[1]);
}

// ---------------------------------------------------------------------------
extern "C" void kernel_launch(void* const* d_in, const int* in_sizes, int n_in,
                              void* d_out, int out_size, void* d_ws, size_t ws_size,
                              hipStream_t stream) {
    const float* x     = (const float*)d_in[0];
    const float* K     = (const float*)d_in[1];
    const float* fc_w  = (const float*)d_in[2];
    const float* fc_b  = (const float*)d_in[3];
    const float* gamma = (const float*)d_in[4];
    const float* beta  = (const float*)d_in[5];
    const float* mmean = (const float*)d_in[6];
    const float* mvar  = (const float*)d_in[7];
    float* out = (float*)d_out;

    unsigned short* KbT = (unsigned short*)d_ws;            // 4 MB
    unsigned short* W2  = KbT + 2097152;                    // 4 MB
    unsigned short* Kjj = W2 + 2097152;                     // 32 KB
    const size_t tab_bytes = 8421376;
    float* yp = (float*)((char*)d_ws + tab_bytes);

    // NJ=16 doubles occupancy (1024 blocks = 4/CU = 16 waves/CU) at +16.8MB ws.
    int nj = (ws_size >= tab_bytes + (size_t)16 * 4096 * 128 * 4) ? 16 : 8;
    int jpc = 128 / nj;

    hipLaunchKernelGGL(ife_prep3, dim3(512),     dim3(256), 0, stream, K, fc_w, KbT, W2, Kjj);
    hipLaunchKernelGGL(ife_main2, dim3(64 * nj), dim3(256), 0, stream, x, KbT, W2, Kjj, yp, jpc);
    hipLaunchKernelGGL(ife_final, dim3(4096),    dim3(128), 0, stream,
                       yp, fc_b, gamma, beta, mmean, mvar, out, nj);
}

// Round 7
// 183.489 us; speedup vs baseline: 1.2339x; 1.2339x over previous
//
#include <hip/hip_runtime.h>

// B=4096 rows, F=128 features, A=8 heads, U=10 units (padded to 16).
// y = softmax_f( BN( (1/F) sum_{j,a,u} softmax_u(Z[j,a,b,:])[u] exp(2K[j,a,f,u]) fc_w[a] + fc_b ) )
// Z[j,a,b,u] = sum_f x[b,f] K[j,a,f,u] - x[b,j] K[j,a,j,u]
//
// MFMA plan (16x16x32 bf16, fp32 accum):
//   GEMM1 (transposed): Z^T[u][b] = KbT[u][f] * x[f][b]  -> u lives in-lane for softmax
//   GEMM2: acc[b][f] += P[b][k=(a-pair,u)] * W2[k][f], k=32 packs 2 heads per MFMA
// Grid: 64 b-tiles x NJ j-chunks; NJ=16 when ws allows (1024 blocks = 4/CU).
//
// NOTE on launch_bounds: (256,4) forces a 64-VGPR target -> xf[16] spills to
// scratch (measured R6: FETCH 34->215MB, WRITE 16->242MB, main 98->151us).
// (256,2) gives 84 VGPR, no spill; 84 <= 128 so HW still runs 4 waves/SIMD.

typedef __attribute__((ext_vector_type(8))) short short8v;
typedef __attribute__((ext_vector_type(4))) float f32x4;

__device__ inline unsigned short f2bf(float f) {
    union { float f; unsigned u; } c; c.f = f;
    return (unsigned short)((c.u + 0x7FFFu + ((c.u >> 16) & 1u)) >> 16);
}
__device__ inline float bf2f(unsigned short h) {
    union { unsigned u; float f; } c; c.u = ((unsigned)h) << 16;
    return c.f;
}

// ---------------------------------------------------------------------------
// Prep (coalesced): block = (j, pair p). Computes
//   KbT[j][a][u16][f128] bf16, W2[j][p][f128][k32] bf16 (k=ai*16+u), Kjj[j][a][u16].
// W2 tile staged in LDS [f][k] then written out dword-coalesced.
// ---------------------------------------------------------------------------
__global__ __launch_bounds__(256) void ife_prep3(
    const float* __restrict__ K, const float* __restrict__ fc_w,
    unsigned short* __restrict__ KbT, unsigned short* __restrict__ W2,
    unsigned short* __restrict__ Kjj) {
    const int j = blockIdx.x >> 2, p = blockIdx.x & 3;
    const int t = threadIdx.x;
    __shared__ unsigned short wt[128 * 32];      // [f][k]  8KB
    __shared__ unsigned short kt[2 * 128 * 16];  // [ai][f][u]  8KB
    const int ai = t >> 7, f = t & 127, a = p * 2 + ai;
    const float* src = K + (size_t)((j * 8 + a) * 128 + f) * 10;
    const float wscale = fc_w[a] * (1.0f / 128.0f);
    float kv[10];
#pragma unroll
    for (int u = 0; u < 10; ++u) kv[u] = src[u];
#pragma unroll
    for (int u = 0; u < 16; ++u) {
        unsigned short kb = (u < 10) ? f2bf(kv[u]) : (unsigned short)0;
        kt[(ai * 128 + f) * 16 + u] = kb;
        wt[f * 32 + ai * 16 + u] =
            (u < 10) ? f2bf(__expf(2.0f * kv[u]) * wscale) : (unsigned short)0;
        if (f == j) Kjj[(size_t)(j * 8 + a) * 16 + u] = kb;
    }
    __syncthreads();
    // W2 tile out: 2048 dwords, fully coalesced
    {
        const unsigned* s = (const unsigned*)wt;
        unsigned* d = (unsigned*)(W2 + (size_t)(j * 4 + p) * 128 * 32);
#pragma unroll
        for (int i = 0; i < 8; ++i) d[i * 256 + t] = s[i * 256 + t];
    }
    // KbT out for both heads: per head 1024 dwords, coalesced (transpose from kt)
#pragma unroll
    for (int a2 = 0; a2 < 2; ++a2) {
        unsigned* d = (unsigned*)(KbT + (size_t)((j * 8 + p * 2 + a2) * 16) * 128);
#pragma unroll
        for (int i = 0; i < 4; ++i) {
            int dd = i * 256 + t;
            int u = dd >> 6, f2 = (dd & 63) * 2;
            unsigned lo = kt[(a2 * 128 + f2) * 16 + u];
            unsigned hi = kt[(a2 * 128 + f2 + 1) * 16 + u];
            d[dd] = lo | (hi << 16);
        }
    }
}

// ---------------------------------------------------------------------------
// Main: block = 256 threads (4 waves), 64-row b-tile, one j-chunk (jpc j's).
// Wave w: GEMM1+softmax for heads a=2w,2w+1 (pair w); GEMM2 f-block w*32.
// ---------------------------------------------------------------------------
__global__ __launch_bounds__(256, 2) void ife_main2(
    const float* __restrict__ x, const unsigned short* __restrict__ KbT,
    const unsigned short* __restrict__ W2, const unsigned short* __restrict__ Kjj,
    float* __restrict__ yp, int jpc) {
    __shared__ unsigned xb[64 * 64];    // x tile bf16x2, f-octet XOR-swizzled (16KB)
    __shared__ unsigned pb[4 * 64 * 16];// P bf16x2 [pair][b][k-dword], swizzled (16KB)

    const int t = threadIdx.x;
    const int btile = blockIdx.x & 63;
    const int chunk = blockIdx.x >> 6;
    const int b0 = btile * 64;
    const int lane = t & 63;
    const int wv = __builtin_amdgcn_readfirstlane(t >> 6);
    const int lr = lane & 15;   // row/col within a 16-tile
    const int lg = lane >> 4;   // k-octet group (0..3)

    // stage x -> bf16 LDS: dword dw holds f=2dw,2dw+1; octet g stored at g^(b&7)
    for (int i = t; i < 64 * 64; i += 256) {
        int b = i >> 6, dw = i & 63;
        float2 v = *reinterpret_cast<const float2*>(x + (size_t)(b0 + b) * 128 + dw * 2);
        unsigned pk = (unsigned)f2bf(v.x) | ((unsigned)f2bf(v.y) << 16);
        int g = dw >> 2;
        xb[b * 64 + (((g ^ (b & 7)) << 2) | (dw & 3))] = pk;
    }
    __syncthreads();

    // x B-fragments, j- and a-invariant: held for the whole block.
    // frag(ks,nt): col b = nt*16+lr, k(f) = ks*32 + lg*8 .. +8
    short8v xf[16];
#pragma unroll
    for (int ks = 0; ks < 4; ++ks)
#pragma unroll
        for (int nt = 0; nt < 4; ++nt) {
            int b = nt * 16 + lr;
            int g = ks * 4 + lg;
            xf[ks * 4 + nt] = *reinterpret_cast<const short8v*>(
                &xb[b * 64 + ((g ^ (b & 7)) << 2)]);
        }

    f32x4 acc[4][2];
#pragma unroll
    for (int mt = 0; mt < 4; ++mt)
#pragma unroll
        for (int nt = 0; nt < 2; ++nt) acc[mt][nt] = f32x4{0.f, 0.f, 0.f, 0.f};

    const int ub = lg * 4;      // this lane's base u (GEMM1 D rows)

#pragma unroll 1
    for (int jj = 0; jj < jpc; ++jj) {
        const int j = chunk * jpc + jj;
        // ---------- GEMM1 + softmax + P-write for this wave's 2 heads ----------
#pragma unroll
        for (int ai = 0; ai < 2; ++ai) {
            const int a = wv * 2 + ai;
            const size_t kbase = (size_t)(j * 8 + a) * 16;
            short8v af[4];   // A-frag: row u=lr, k(f)=ks*32+lg*8
#pragma unroll
            for (int ks = 0; ks < 4; ++ks)
                af[ks] = *reinterpret_cast<const short8v*>(
                    KbT + (kbase + lr) * 128 + ks * 32 + lg * 8);
            f32x4 z[4];
#pragma unroll
            for (int nt = 0; nt < 4; ++nt) z[nt] = f32x4{0.f, 0.f, 0.f, 0.f};
#pragma unroll
            for (int ks = 0; ks < 4; ++ks)
#pragma unroll
                for (int nt = 0; nt < 4; ++nt)
                    z[nt] = __builtin_amdgcn_mfma_f32_16x16x32_bf16(
                        af[ks], xf[ks * 4 + nt], z[nt], 0, 0, 0);
            // rank-1 correction: z[u][b] -= K[j,a,j,u] * x[b,j]
            unsigned short kj0, kj1, kj2, kj3;
            {
                const unsigned short* kp = Kjj + kbase + ub;
                kj0 = kp[0]; kj1 = kp[1]; kj2 = kp[2]; kj3 = kp[3];
            }
            const int gj = j >> 3;
#pragma unroll
            for (int nt = 0; nt < 4; ++nt) {
                int b = nt * 16 + lr;
                unsigned pkx = xb[b * 64 + (((gj ^ (b & 7)) << 2) | ((j >> 1) & 3))];
                float xbj = bf2f((unsigned short)((j & 1) ? (pkx >> 16) : (pkx & 0xFFFFu)));
                z[nt][0] = fmaf(-bf2f(kj0), xbj, z[nt][0]);
                z[nt][1] = fmaf(-bf2f(kj1), xbj, z[nt][1]);
                z[nt][2] = fmaf(-bf2f(kj2), xbj, z[nt][2]);
                z[nt][3] = fmaf(-bf2f(kj3), xbj, z[nt][3]);
            }
            // softmax over u (in-lane 4 + shfl_xor 16/32), mask u>=10, pack to pb
#pragma unroll
            for (int nt = 0; nt < 4; ++nt) {
                float m = -3.0e38f;
#pragma unroll
                for (int q = 0; q < 4; ++q)
                    m = (ub + q < 10) ? fmaxf(m, z[nt][q]) : m;
                m = fmaxf(m, __shfl_xor(m, 16, 64));
                m = fmaxf(m, __shfl_xor(m, 32, 64));
                float e0 = (ub + 0 < 10) ? __expf(z[nt][0] - m) : 0.f;
                float e1 = (ub + 1 < 10) ? __expf(z[nt][1] - m) : 0.f;
                float e2 = (ub + 2 < 10) ? __expf(z[nt][2] - m) : 0.f;
                float e3 = (ub + 3 < 10) ? __expf(z[nt][3] - m) : 0.f;
                float s = e0 + e1 + e2 + e3;
                s += __shfl_xor(s, 16, 64);
                s += __shfl_xor(s, 32, 64);
                float inv = 1.0f / s;
                int b = nt * 16 + lr;
                unsigned pk0 = (unsigned)f2bf(e0 * inv) | ((unsigned)f2bf(e1 * inv) << 16);
                unsigned pk1 = (unsigned)f2bf(e2 * inv) | ((unsigned)f2bf(e3 * inv) << 16);
                int dw0 = ai * 8 + lg * 2;           // k-dword col (k = ai*16 + u)
                int base = (wv * 64 + b) * 16;
                int swz = (b >> 1) & 3;
                pb[base + ((((dw0 >> 2) ^ swz) << 2) | (dw0 & 3))] = pk0;
                pb[base + ((((dw0 + 1) >> 2) ^ swz) << 2) + ((dw0 + 1) & 3)] = pk1;
            }
        }
        __syncthreads();
        // ---------- GEMM2: acc[b][f-block wv*32] += P * W2 ----------
#pragma unroll
        for (int p = 0; p < 4; ++p) {
            short8v wf[2];   // B-frag: col f = wv*32+nt*16+lr, k = lg*8..+8
#pragma unroll
            for (int nt = 0; nt < 2; ++nt) {
                int f = wv * 32 + nt * 16 + lr;
                wf[nt] = *reinterpret_cast<const short8v*>(
                    W2 + (((size_t)(j * 4 + p) * 128 + f) * 32) + lg * 8);
            }
#pragma unroll
            for (int mt = 0; mt < 4; ++mt) {
                int b = mt * 16 + lr;
                short8v pf = *reinterpret_cast<const short8v*>(
                    &pb[(p * 64 + b) * 16 + ((lg ^ ((b >> 1) & 3)) << 2)]);
#pragma unroll
                for (int nt = 0; nt < 2; ++nt)
                    acc[mt][nt] = __builtin_amdgcn_mfma_f32_16x16x32_bf16(
                        pf, wf[nt], acc[mt][nt], 0, 0, 0);
            }
        }
        __syncthreads();
    }
    // store partials: D layout col=lr (f), row=lg*4+q (b)
    float* ypb = yp + ((size_t)chunk * 4096 + b0) * 128;
#pragma unroll
    for (int mt = 0; mt < 4; ++mt)
#pragma unroll
        for (int nt = 0; nt < 2; ++nt) {
            int f = wv * 32 + nt * 16 + lr;
#pragma unroll
            for (int q = 0; q < 4; ++q) {
                int b = mt * 16 + lg * 4 + q;
                ypb[(size_t)b * 128 + f] = acc[mt][nt][q];
            }
        }
}

// ---------------------------------------------------------------------------
// Finalize: sum nj partials, + fc_b, inference BN, row-softmax over F=128.
// ---------------------------------------------------------------------------
__global__ void ife_final(const float* __restrict__ yp, const float* __restrict__ fc_b,
                          const float* __restrict__ gamma, const float* __restrict__ beta,
                          const float* __restrict__ mmean, const float* __restrict__ mvar,
                          float* __restrict__ out, int nj) {
    const int b = blockIdx.x;
    const int f = threadIdx.x;  // 128
    float s = 0.f;
#pragma unroll 1
    for (int n = 0; n < nj; ++n)
        s += yp[((size_t)n * 4096 + b) * 128 + f];
    const float scale = gamma[0] * rsqrtf(mvar[0] + 1e-3f);
    float y = (s + fc_b[0] - mmean[0]) * scale + beta[0];

    __shared__ float redm[2], reds[2];
    float m = y;
#pragma unroll
    for (int o = 32; o >= 1; o >>= 1) m = fmaxf(m, __shfl_xor(m, o, 64));
    const int wid = f >> 6;
    if ((f & 63) == 0) redm[wid] = m;
    __syncthreads();
    m = fmaxf(redm[0], redm[1]);
    float e = __expf(y - m);
    float ss = e;
#pragma unroll
    for (int o = 32; o >= 1; o >>= 1) ss += __shfl_xor(ss, o, 64);
    if ((f & 63) == 0) reds[wid] = ss;
    __syncthreads();
    out[(size_t)b * 128 + f] = e / (reds[0] + reds[1]);
}

// ---------------------------------------------------------------------------
extern "C" void kernel_launch(void* const* d_in, const int* in_sizes, int n_in,
                              void* d_out, int out_size, void* d_ws, size_t ws_size,
                              hipStream_t stream) {
    const float* x     = (const float*)d_in[0];
    const float* K     = (const float*)d_in[1];
    const float* fc_w  = (const float*)d_in[2];
    const float* fc_b  = (const float*)d_in[3];
    const float* gamma = (const float*)d_in[4];
    const float* beta  = (const float*)d_in[5];
    const float* mmean = (const float*)d_in[6];
    const float* mvar  = (const float*)d_in[7];
    float* out = (float*)d_out;

    unsigned short* KbT = (unsigned short*)d_ws;            // 4 MB
    unsigned short* W2  = KbT + 2097152;                    // 4 MB
    unsigned short* Kjj = W2 + 2097152;                     // 32 KB
    const size_t tab_bytes = 8421376;
    float* yp = (float*)((char*)d_ws + tab_bytes);

    // NJ=16: 1024 blocks = 4/CU = 16 waves/CU (84 VGPR <= 128 allows 4 waves/SIMD).
    int nj = (ws_size >= tab_bytes + (size_t)16 * 4096 * 128 * 4) ? 16 : 8;
    int jpc = 128 / nj;

    hipLaunchKernelGGL(ife_prep3, dim3(512),     dim3(256), 0, stream, K, fc_w, KbT, W2, Kjj);
    hipLaunchKernelGGL(ife_main2, dim3(64 * nj), dim3(256), 0, stream, x, KbT, W2, Kjj, yp, jpc);
    hipLaunchKernelGGL(ife_final, dim3(4096),    dim3(128), 0, stream,
                       yp, fc_b, gamma, beta, mmean, mvar, out, nj);
}

// Round 8
// 156.550 us; speedup vs baseline: 1.4462x; 1.1721x over previous
//
#include <hip/hip_runtime.h>

// B=4096 rows, F=128 features, A=8 heads, U=10 units (padded to 16).
// y = softmax_f( BN( (1/F) sum_{j,a,u} softmax_u(Z[j,a,b,:])[u] exp(2K[j,a,f,u]) fc_w[a] + fc_b ) )
// Z[j,a,b,u] = sum_f x[b,f] K[j,a,f,u] - x[b,j] K[j,a,j,u]
//
// MFMA plan (16x16x32 bf16, fp32 accum):
//   GEMM1 (transposed): Z^T[u][b] = KbT[u][f] * x[f][b]  -> u lives in-lane for softmax
//   GEMM2: acc[b][f] += P[b][k=(a-pair,u)] * W2[k][f], k=32 packs 2 heads per MFMA
//
// Register history (measured): R6 launch_bounds(256,4) -> 64-VGPR target -> xf
// spilled (FETCH 215MB, 151us). R7 (256,2) -> no spill but xf[16]=64 regs pushes
// total/wave to ~190 -> 2 waves/SIMD -> occupancy stuck 24%, main 110us.
// R8: drop xf register cache, read x frags from LDS inside the k-loop ->
// ~110 total regs -> 4 waves/SIMD; NJ=16 grid (4 blocks/CU) becomes usable.

typedef __attribute__((ext_vector_type(8))) short short8v;
typedef __attribute__((ext_vector_type(4))) float f32x4;

__device__ inline unsigned short f2bf(float f) {
    union { float f; unsigned u; } c; c.f = f;
    return (unsigned short)((c.u + 0x7FFFu + ((c.u >> 16) & 1u)) >> 16);
}
__device__ inline float bf2f(unsigned short h) {
    union { unsigned u; float f; } c; c.u = ((unsigned)h) << 16;
    return c.f;
}

// ---------------------------------------------------------------------------
// Prep (coalesced): block = (j, pair p). Computes
//   KbT[j][a][u16][f128] bf16, W2[j][p][f128][k32] bf16 (k=ai*16+u), Kjj[j][a][u16].
// W2 tile staged in LDS [f][k] then written out dword-coalesced.
// ---------------------------------------------------------------------------
__global__ __launch_bounds__(256) void ife_prep3(
    const float* __restrict__ K, const float* __restrict__ fc_w,
    unsigned short* __restrict__ KbT, unsigned short* __restrict__ W2,
    unsigned short* __restrict__ Kjj) {
    const int j = blockIdx.x >> 2, p = blockIdx.x & 3;
    const int t = threadIdx.x;
    __shared__ unsigned short wt[128 * 32];      // [f][k]  8KB
    __shared__ unsigned short kt[2 * 128 * 16];  // [ai][f][u]  8KB
    const int ai = t >> 7, f = t & 127, a = p * 2 + ai;
    const float* src = K + (size_t)((j * 8 + a) * 128 + f) * 10;
    const float wscale = fc_w[a] * (1.0f / 128.0f);
    float kv[10];
#pragma unroll
    for (int u = 0; u < 10; ++u) kv[u] = src[u];
#pragma unroll
    for (int u = 0; u < 16; ++u) {
        unsigned short kb = (u < 10) ? f2bf(kv[u]) : (unsigned short)0;
        kt[(ai * 128 + f) * 16 + u] = kb;
        wt[f * 32 + ai * 16 + u] =
            (u < 10) ? f2bf(__expf(2.0f * kv[u]) * wscale) : (unsigned short)0;
        if (f == j) Kjj[(size_t)(j * 8 + a) * 16 + u] = kb;
    }
    __syncthreads();
    // W2 tile out: 2048 dwords, fully coalesced
    {
        const unsigned* s = (const unsigned*)wt;
        unsigned* d = (unsigned*)(W2 + (size_t)(j * 4 + p) * 128 * 32);
#pragma unroll
        for (int i = 0; i < 8; ++i) d[i * 256 + t] = s[i * 256 + t];
    }
    // KbT out for both heads: per head 1024 dwords, coalesced (transpose from kt)
#pragma unroll
    for (int a2 = 0; a2 < 2; ++a2) {
        unsigned* d = (unsigned*)(KbT + (size_t)((j * 8 + p * 2 + a2) * 16) * 128);
#pragma unroll
        for (int i = 0; i < 4; ++i) {
            int dd = i * 256 + t;
            int u = dd >> 6, f2 = (dd & 63) * 2;
            unsigned lo = kt[(a2 * 128 + f2) * 16 + u];
            unsigned hi = kt[(a2 * 128 + f2 + 1) * 16 + u];
            d[dd] = lo | (hi << 16);
        }
    }
}

// ---------------------------------------------------------------------------
// Main: block = 256 threads (4 waves), 64-row b-tile, one j-chunk (jpc j's).
// Wave w: GEMM1+softmax for heads a=2w,2w+1 (pair w); GEMM2 f-block w*32.
// x fragments are read from LDS inside the k-loop (NOT register-cached).
// ---------------------------------------------------------------------------
__global__ __launch_bounds__(256, 2) void ife_main2(
    const float* __restrict__ x, const unsigned short* __restrict__ KbT,
    const unsigned short* __restrict__ W2, const unsigned short* __restrict__ Kjj,
    float* __restrict__ yp, int jpc) {
    __shared__ unsigned xb[64 * 64];    // x tile bf16x2, f-octet XOR-swizzled (16KB)
    __shared__ unsigned pb[4 * 64 * 16];// P bf16x2 [pair][b][k-dword], swizzled (16KB)

    const int t = threadIdx.x;
    const int btile = blockIdx.x & 63;
    const int chunk = blockIdx.x >> 6;
    const int b0 = btile * 64;
    const int lane = t & 63;
    const int wv = __builtin_amdgcn_readfirstlane(t >> 6);
    const int lr = lane & 15;   // row/col within a 16-tile
    const int lg = lane >> 4;   // k-octet group (0..3)
    const int bx = lr & 7;      // swizzle key for rows lr, lr+16, ... (16 ≡ 0 mod 8)

    // stage x -> bf16 LDS: dword dw holds f=2dw,2dw+1; octet g stored at g^(b&7)
    for (int i = t; i < 64 * 64; i += 256) {
        int b = i >> 6, dw = i & 63;
        float2 v = *reinterpret_cast<const float2*>(x + (size_t)(b0 + b) * 128 + dw * 2);
        unsigned pk = (unsigned)f2bf(v.x) | ((unsigned)f2bf(v.y) << 16);
        int g = dw >> 2;
        xb[b * 64 + (((g ^ (b & 7)) << 2) | (dw & 3))] = pk;
    }
    __syncthreads();

    f32x4 acc[4][2];
#pragma unroll
    for (int mt = 0; mt < 4; ++mt)
#pragma unroll
        for (int nt = 0; nt < 2; ++nt) acc[mt][nt] = f32x4{0.f, 0.f, 0.f, 0.f};

    const int ub = lg * 4;      // this lane's base u (GEMM1 D rows)

#pragma unroll 1
    for (int jj = 0; jj < jpc; ++jj) {
        const int j = chunk * jpc + jj;
        // ---------- GEMM1 + softmax + P-write for this wave's 2 heads ----------
#pragma unroll
        for (int ai = 0; ai < 2; ++ai) {
            const int a = wv * 2 + ai;
            const size_t kbase = (size_t)(j * 8 + a) * 16;
            short8v af[4];   // A-frag: row u=lr, k(f)=ks*32+lg*8
#pragma unroll
            for (int ks = 0; ks < 4; ++ks)
                af[ks] = *reinterpret_cast<const short8v*>(
                    KbT + (kbase + lr) * 128 + ks * 32 + lg * 8);
            f32x4 z[4];
#pragma unroll
            for (int nt = 0; nt < 4; ++nt) z[nt] = f32x4{0.f, 0.f, 0.f, 0.f};
            // x B-frags streamed from LDS each use (saves 64 VGPRs vs caching)
#pragma unroll
            for (int ks = 0; ks < 4; ++ks) {
                const int xoff = ((ks * 4 + lg) ^ bx) << 2;
#pragma unroll
                for (int nt = 0; nt < 4; ++nt) {
                    short8v xv = *reinterpret_cast<const short8v*>(
                        &xb[(nt * 16 + lr) * 64 + xoff]);
                    z[nt] = __builtin_amdgcn_mfma_f32_16x16x32_bf16(
                        af[ks], xv, z[nt], 0, 0, 0);
                }
            }
            // rank-1 correction: z[u][b] -= K[j,a,j,u] * x[b,j]
            unsigned short kj0, kj1, kj2, kj3;
            {
                const unsigned short* kp = Kjj + kbase + ub;
                kj0 = kp[0]; kj1 = kp[1]; kj2 = kp[2]; kj3 = kp[3];
            }
            const int gj = j >> 3;
#pragma unroll
            for (int nt = 0; nt < 4; ++nt) {
                int b = nt * 16 + lr;
                unsigned pkx = xb[b * 64 + (((gj ^ (b & 7)) << 2) | ((j >> 1) & 3))];
                float xbj = bf2f((unsigned short)((j & 1) ? (pkx >> 16) : (pkx & 0xFFFFu)));
                z[nt][0] = fmaf(-bf2f(kj0), xbj, z[nt][0]);
                z[nt][1] = fmaf(-bf2f(kj1), xbj, z[nt][1]);
                z[nt][2] = fmaf(-bf2f(kj2), xbj, z[nt][2]);
                z[nt][3] = fmaf(-bf2f(kj3), xbj, z[nt][3]);
            }
            // softmax over u (in-lane 4 + shfl_xor 16/32), mask u>=10, pack to pb
#pragma unroll
            for (int nt = 0; nt < 4; ++nt) {
                float m = -3.0e38f;
#pragma unroll
                for (int q = 0; q < 4; ++q)
                    m = (ub + q < 10) ? fmaxf(m, z[nt][q]) : m;
                m = fmaxf(m, __shfl_xor(m, 16, 64));
                m = fmaxf(m, __shfl_xor(m, 32, 64));
                float e0 = (ub + 0 < 10) ? __expf(z[nt][0] - m) : 0.f;
                float e1 = (ub + 1 < 10) ? __expf(z[nt][1] - m) : 0.f;
                float e2 = (ub + 2 < 10) ? __expf(z[nt][2] - m) : 0.f;
                float e3 = (ub + 3 < 10) ? __expf(z[nt][3] - m) : 0.f;
                float s = e0 + e1 + e2 + e3;
                s += __shfl_xor(s, 16, 64);
                s += __shfl_xor(s, 32, 64);
                float inv = 1.0f / s;
                int b = nt * 16 + lr;
                unsigned pk0 = (unsigned)f2bf(e0 * inv) | ((unsigned)f2bf(e1 * inv) << 16);
                unsigned pk1 = (unsigned)f2bf(e2 * inv) | ((unsigned)f2bf(e3 * inv) << 16);
                int dw0 = ai * 8 + lg * 2;           // k-dword col (k = ai*16 + u)
                int base = (wv * 64 + b) * 16;
                int swz = (b >> 1) & 3;
                pb[base + ((((dw0 >> 2) ^ swz) << 2) | (dw0 & 3))] = pk0;
                pb[base + ((((dw0 + 1) >> 2) ^ swz) << 2) + ((dw0 + 1) & 3)] = pk1;
            }
        }
        __syncthreads();
        // ---------- GEMM2: acc[b][f-block wv*32] += P * W2 ----------
#pragma unroll
        for (int p = 0; p < 4; ++p) {
            short8v wf[2];   // B-frag: col f = wv*32+nt*16+lr, k = lg*8..+8
#pragma unroll
            for (int nt = 0; nt < 2; ++nt) {
                int f = wv * 32 + nt * 16 + lr;
                wf[nt] = *reinterpret_cast<const short8v*>(
                    W2 + (((size_t)(j * 4 + p) * 128 + f) * 32) + lg * 8);
            }
#pragma unroll
            for (int mt = 0; mt < 4; ++mt) {
                int b = mt * 16 + lr;
                short8v pf = *reinterpret_cast<const short8v*>(
                    &pb[(p * 64 + b) * 16 + ((lg ^ ((b >> 1) & 3)) << 2)]);
#pragma unroll
                for (int nt = 0; nt < 2; ++nt)
                    acc[mt][nt] = __builtin_amdgcn_mfma_f32_16x16x32_bf16(
                        pf, wf[nt], acc[mt][nt], 0, 0, 0);
            }
        }
        __syncthreads();
    }
    // store partials: D layout col=lr (f), row=lg*4+q (b)
    float* ypb = yp + ((size_t)chunk * 4096 + b0) * 128;
#pragma unroll
    for (int mt = 0; mt < 4; ++mt)
#pragma unroll
        for (int nt = 0; nt < 2; ++nt) {
            int f = wv * 32 + nt * 16 + lr;
#pragma unroll
            for (int q = 0; q < 4; ++q) {
                int b = mt * 16 + lg * 4 + q;
                ypb[(size_t)b * 128 + f] = acc[mt][nt][q];
            }
        }
}

// ---------------------------------------------------------------------------
// Finalize: sum nj partials, + fc_b, inference BN, row-softmax over F=128.
// ---------------------------------------------------------------------------
__global__ void ife_final(const float* __restrict__ yp, const float* __restrict__ fc_b,
                          const float* __restrict__ gamma, const float* __restrict__ beta,
                          const float* __restrict__ mmean, const float* __restrict__ mvar,
                          float* __restrict__ out, int nj) {
    const int b = blockIdx.x;
    const int f = threadIdx.x;  // 128
    float s = 0.f;
#pragma unroll 1
    for (int n = 0; n < nj; ++n)
        s += yp[((size_t)n * 4096 + b) * 128 + f];
    const float scale = gamma[0] * rsqrtf(mvar[0] + 1e-3f);
    float y = (s + fc_b[0] - mmean[0]) * scale + beta[0];

    __shared__ float redm[2], reds[2];
    float m = y;
#pragma unroll
    for (int o = 32; o >= 1; o >>= 1) m = fmaxf(m, __shfl_xor(m, o, 64));
    const int wid = f >> 6;
    if ((f & 63) == 0) redm[wid] = m;
    __syncthreads();
    m = fmaxf(redm[0], redm[1]);
    float e = __expf(y - m);
    float ss = e;
#pragma unroll
    for (int o = 32; o >= 1; o >>= 1) ss += __shfl_xor(ss, o, 64);
    if ((f & 63) == 0) reds[wid] = ss;
    __syncthreads();
    out[(size_t)b * 128 + f] = e / (reds[0] + reds[1]);
}

// ---------------------------------------------------------------------------
extern "C" void kernel_launch(void* const* d_in, const int* in_sizes, int n_in,
                              void* d_out, int out_size, void* d_ws, size_t ws_size,
                              hipStream_t stream) {
    const float* x     = (const float*)d_in[0];
    const float* K     = (const float*)d_in[1];
    const float* fc_w  = (const float*)d_in[2];
    const float* fc_b  = (const float*)d_in[3];
    const float* gamma = (const float*)d_in[4];
    const float* beta  = (const float*)d_in[5];
    const float* mmean = (const float*)d_in[6];
    const float* mvar  = (const float*)d_in[7];
    float* out = (float*)d_out;

    unsigned short* KbT = (unsigned short*)d_ws;            // 4 MB
    unsigned short* W2  = KbT + 2097152;                    // 4 MB
    unsigned short* Kjj = W2 + 2097152;                     // 32 KB
    const size_t tab_bytes = 8421376;
    float* yp = (float*)((char*)d_ws + tab_bytes);

    // NJ=16: 1024 blocks = 4 blocks/CU; with ~110 total regs/wave -> 4 waves/SIMD.
    int nj = (ws_size >= tab_bytes + (size_t)16 * 4096 * 128 * 4) ? 16 : 8;
    int jpc = 128 / nj;

    hipLaunchKernelGGL(ife_prep3, dim3(512),     dim3(256), 0, stream, K, fc_w, KbT, W2, Kjj);
    hipLaunchKernelGGL(ife_main2, dim3(64 * nj), dim3(256), 0, stream, x, KbT, W2, Kjj, yp, jpc);
    hipLaunchKernelGGL(ife_final, dim3(4096),    dim3(128), 0, stream,
                       yp, fc_b, gamma, beta, mmean, mvar, out, nj);
}

// Round 11
// 146.704 us; speedup vs baseline: 1.5433x; 1.0671x over previous
//
#include <hip/hip_runtime.h>
#include <hip/hip_bf16.h>

// B=4096 rows, F=128 features, A=8 heads, U=10 units (padded to 16).
// y = softmax_f( BN( (1/F) sum_{j,a,u} softmax_u(Z[j,a,b,:])[u] exp(2K[j,a,f,u]) fc_w[a] + fc_b ) )
// Z[j,a,b,u] = sum_f x[b,f] K[j,a,f,u] - x[b,j] K[j,a,j,u]
//
// MFMA plan (16x16x32 bf16, fp32 accum):
//   GEMM1 (transposed): Z^T[u][b] = KbT[u][f] * x[f][b]  -> u lives in-lane for softmax
//   GEMM2: acc[b][f] += P[b][k=(a-pair,u)] * W2[k][f], k=32 packs 2 heads per MFMA
//
// Measured history: R6 launch_bounds(256,4) -> spill (151us). R7 xf-cached,
// (256,2): 2 waves/SIMD, occ 24%, 110us. R8 x-from-LDS: occ 36%, 78us,
// VALU 50% / Mfma 18% -> VALU glue is the limiter.
// R9: cut VALU in softmax path: (1) no max-subtract (|z|<~10, exp safe),
// (2) v_cvt_pk_bf16_f32 packing via __float22bfloat162_rn, (3) hoist x[b,j].

typedef __attribute__((ext_vector_type(8))) short short8v;
typedef __attribute__((ext_vector_type(4))) float f32x4;

__device__ inline unsigned short f2bf(float f) {
    union { float f; unsigned u; } c; c.f = f;
    return (unsigned short)((c.u + 0x7FFFu + ((c.u >> 16) & 1u)) >> 16);
}
__device__ inline float bf2f(unsigned short h) {
    union { unsigned u; float f; } c; c.u = ((unsigned)h) << 16;
    return c.f;
}
__device__ inline unsigned pack_bf2(float lo, float hi) {
    __hip_bfloat162 h = __float22bfloat162_rn(float2{lo, hi});  // v_cvt_pk_bf16_f32
    union { __hip_bfloat162 h; unsigned u; } c; c.h = h;
    return c.u;
}

// ---------------------------------------------------------------------------
// Prep (coalesced): block = (j, pair p). Computes
//   KbT[j][a][u16][f128] bf16, W2[j][p][f128][k32] bf16 (k=ai*16+u), Kjj[j][a][u16].
// ---------------------------------------------------------------------------
__global__ __launch_bounds__(256) void ife_prep3(
    const float* __restrict__ K, const float* __restrict__ fc_w,
    unsigned short* __restrict__ KbT, unsigned short* __restrict__ W2,
    unsigned short* __restrict__ Kjj) {
    const int j = blockIdx.x >> 2, p = blockIdx.x & 3;
    const int t = threadIdx.x;
    __shared__ unsigned short wt[128 * 32];      // [f][k]  8KB
    __shared__ unsigned short kt[2 * 128 * 16];  // [ai][f][u]  8KB
    const int ai = t >> 7, f = t & 127, a = p * 2 + ai;
    const float* src = K + (size_t)((j * 8 + a) * 128 + f) * 10;
    const float wscale = fc_w[a] * (1.0f / 128.0f);
    float kv[10];
#pragma unroll
    for (int u = 0; u < 10; ++u) kv[u] = src[u];
#pragma unroll
    for (int u = 0; u < 16; ++u) {
        unsigned short kb = (u < 10) ? f2bf(kv[u]) : (unsigned short)0;
        kt[(ai * 128 + f) * 16 + u] = kb;
        wt[f * 32 + ai * 16 + u] =
            (u < 10) ? f2bf(__expf(2.0f * kv[u]) * wscale) : (unsigned short)0;
        if (f == j) Kjj[(size_t)(j * 8 + a) * 16 + u] = kb;
    }
    __syncthreads();
    {
        const unsigned* s = (const unsigned*)wt;
        unsigned* d = (unsigned*)(W2 + (size_t)(j * 4 + p) * 128 * 32);
#pragma unroll
        for (int i = 0; i < 8; ++i) d[i * 256 + t] = s[i * 256 + t];
    }
#pragma unroll
    for (int a2 = 0; a2 < 2; ++a2) {
        unsigned* d = (unsigned*)(KbT + (size_t)((j * 8 + p * 2 + a2) * 16) * 128);
#pragma unroll
        for (int i = 0; i < 4; ++i) {
            int dd = i * 256 + t;
            int u = dd >> 6, f2 = (dd & 63) * 2;
            unsigned lo = kt[(a2 * 128 + f2) * 16 + u];
            unsigned hi = kt[(a2 * 128 + f2 + 1) * 16 + u];
            d[dd] = lo | (hi << 16);
        }
    }
}

// ---------------------------------------------------------------------------
// Main: block = 256 threads (4 waves), 64-row b-tile, one j-chunk (jpc j's).
// Wave w: GEMM1+softmax for heads a=2w,2w+1 (pair w); GEMM2 f-block w*32.
// ---------------------------------------------------------------------------
__global__ __launch_bounds__(256, 2) void ife_main2(
    const float* __restrict__ x, const unsigned short* __restrict__ KbT,
    const unsigned short* __restrict__ W2, const unsigned short* __restrict__ Kjj,
    float* __restrict__ yp, int jpc) {
    __shared__ unsigned xb[64 * 64];    // x tile bf16x2, f-octet XOR-swizzled (16KB)
    __shared__ unsigned pb[4 * 64 * 16];// P bf16x2 [pair][b][k-dword], swizzled (16KB)

    const int t = threadIdx.x;
    const int btile = blockIdx.x & 63;
    const int chunk = blockIdx.x >> 6;
    const int b0 = btile * 64;
    const int lane = t & 63;
    const int wv = __builtin_amdgcn_readfirstlane(t >> 6);
    const int lr = lane & 15;   // row/col within a 16-tile
    const int lg = lane >> 4;   // k-octet group (0..3)
    const int bx = lr & 7;      // swizzle key for rows lr, lr+16, ...

    // stage x -> bf16 LDS: dword dw holds f=2dw,2dw+1; octet g stored at g^(b&7)
    for (int i = t; i < 64 * 64; i += 256) {
        int b = i >> 6, dw = i & 63;
        float2 v = *reinterpret_cast<const float2*>(x + (size_t)(b0 + b) * 128 + dw * 2);
        unsigned pk = pack_bf2(v.x, v.y);
        int g = dw >> 2;
        xb[b * 64 + (((g ^ (b & 7)) << 2) | (dw & 3))] = pk;
    }
    __syncthreads();

    f32x4 acc[4][2];
#pragma unroll
    for (int mt = 0; mt < 4; ++mt)
#pragma unroll
        for (int nt = 0; nt < 2; ++nt) acc[mt][nt] = f32x4{0.f, 0.f, 0.f, 0.f};

    const int ub = lg * 4;      // this lane's base u (GEMM1 D rows)

#pragma unroll 1
    for (int jj = 0; jj < jpc; ++jj) {
        const int j = chunk * jpc + jj;
        // rank-1 x[b,j] values: head-invariant, hoisted out of the ai loop
        const int gj = j >> 3;
        float xbj[4];
#pragma unroll
        for (int nt = 0; nt < 4; ++nt) {
            int b = nt * 16 + lr;
            unsigned pkx = xb[b * 64 + (((gj ^ (b & 7)) << 2) | ((j >> 1) & 3))];
            xbj[nt] = bf2f((unsigned short)((j & 1) ? (pkx >> 16) : (pkx & 0xFFFFu)));
        }
        // ---------- GEMM1 + softmax + P-write for this wave's 2 heads ----------
#pragma unroll
        for (int ai = 0; ai < 2; ++ai) {
            const int a = wv * 2 + ai;
            const size_t kbase = (size_t)(j * 8 + a) * 16;
            short8v af[4];   // A-frag: row u=lr, k(f)=ks*32+lg*8
#pragma unroll
            for (int ks = 0; ks < 4; ++ks)
                af[ks] = *reinterpret_cast<const short8v*>(
                    KbT + (kbase + lr) * 128 + ks * 32 + lg * 8);
            f32x4 z[4];
#pragma unroll
            for (int nt = 0; nt < 4; ++nt) z[nt] = f32x4{0.f, 0.f, 0.f, 0.f};
            // x B-frags streamed from LDS each use (saves 64 VGPRs vs caching)
#pragma unroll
            for (int ks = 0; ks < 4; ++ks) {
                const int xoff = ((ks * 4 + lg) ^ bx) << 2;
#pragma unroll
                for (int nt = 0; nt < 4; ++nt) {
                    short8v xv = *reinterpret_cast<const short8v*>(
                        &xb[(nt * 16 + lr) * 64 + xoff]);
                    z[nt] = __builtin_amdgcn_mfma_f32_16x16x32_bf16(
                        af[ks], xv, z[nt], 0, 0, 0);
                }
            }
            // rank-1 correction: z[u][b] -= K[j,a,j,u] * x[b,j]
            unsigned short kj0, kj1, kj2, kj3;
            {
                const unsigned short* kp = Kjj + kbase + ub;
                kj0 = kp[0]; kj1 = kp[1]; kj2 = kp[2]; kj3 = kp[3];
            }
#pragma unroll
            for (int nt = 0; nt < 4; ++nt) {
                z[nt][0] = fmaf(-bf2f(kj0), xbj[nt], z[nt][0]);
                z[nt][1] = fmaf(-bf2f(kj1), xbj[nt], z[nt][1]);
                z[nt][2] = fmaf(-bf2f(kj2), xbj[nt], z[nt][2]);
                z[nt][3] = fmaf(-bf2f(kj3), xbj[nt], z[nt][3]);
            }
            // softmax over u WITHOUT max-subtraction (|z| <~ 10 << 88, safe):
            // e = exp(z) masked to u<10; sum in-lane + 2 shfl; pack via cvt_pk.
#pragma unroll
            for (int nt = 0; nt < 4; ++nt) {
                float e0 = (ub + 0 < 10) ? __expf(z[nt][0]) : 0.f;
                float e1 = (ub + 1 < 10) ? __expf(z[nt][1]) : 0.f;
                float e2 = (ub + 2 < 10) ? __expf(z[nt][2]) : 0.f;
                float e3 = (ub + 3 < 10) ? __expf(z[nt][3]) : 0.f;
                float s = e0 + e1 + e2 + e3;
                s += __shfl_xor(s, 16, 64);
                s += __shfl_xor(s, 32, 64);
                float inv = 1.0f / s;
                int b = nt * 16 + lr;
                unsigned pk0 = pack_bf2(e0 * inv, e1 * inv);
                unsigned pk1 = pack_bf2(e2 * inv, e3 * inv);
                int dw0 = ai * 8 + lg * 2;           // k-dword col (k = ai*16 + u)
                int base = (wv * 64 + b) * 16;
                int swz = (b >> 1) & 3;
                pb[base + ((((dw0 >> 2) ^ swz) << 2) | (dw0 & 3))] = pk0;
                pb[base + ((((dw0 + 1) >> 2) ^ swz) << 2) + ((dw0 + 1) & 3)] = pk1;
            }
        }
        __syncthreads();
        // ---------- GEMM2: acc[b][f-block wv*32] += P * W2 ----------
#pragma unroll
        for (int p = 0; p < 4; ++p) {
            short8v wf[2];   // B-frag: col f = wv*32+nt*16+lr, k = lg*8..+8
#pragma unroll
            for (int nt = 0; nt < 2; ++nt) {
                int f = wv * 32 + nt * 16 + lr;
                wf[nt] = *reinterpret_cast<const short8v*>(
                    W2 + (((size_t)(j * 4 + p) * 128 + f) * 32) + lg * 8);
            }
#pragma unroll
            for (int mt = 0; mt < 4; ++mt) {
                int b = mt * 16 + lr;
                short8v pf = *reinterpret_cast<const short8v*>(
                    &pb[(p * 64 + b) * 16 + ((lg ^ ((b >> 1) & 3)) << 2)]);
#pragma unroll
                for (int nt = 0; nt < 2; ++nt)
                    acc[mt][nt] = __builtin_amdgcn_mfma_f32_16x16x32_bf16(
                        pf, wf[nt], acc[mt][nt], 0, 0, 0);
            }
        }
        __syncthreads();
    }
    // store partials: D layout col=lr (f), row=lg*4+q (b)
    float* ypb = yp + ((size_t)chunk * 4096 + b0) * 128;
#pragma unroll
    for (int mt = 0; mt < 4; ++mt)
#pragma unroll
        for (int nt = 0; nt < 2; ++nt) {
            int f = wv * 32 + nt * 16 + lr;
#pragma unroll
            for (int q = 0; q < 4; ++q) {
                int b = mt * 16 + lg * 4 + q;
                ypb[(size_t)b * 128 + f] = acc[mt][nt][q];
            }
        }
}

// ---------------------------------------------------------------------------
// Finalize: sum nj partials, + fc_b, inference BN, row-softmax over F=128.
// ---------------------------------------------------------------------------
__global__ void ife_final(const float* __restrict__ yp, const float* __restrict__ fc_b,
                          const float* __restrict__ gamma, const float* __restrict__ beta,
                          const float* __restrict__ mmean, const float* __restrict__ mvar,
                          float* __restrict__ out, int nj) {
    const int b = blockIdx.x;
    const int f = threadIdx.x;  // 128
    float s = 0.f;
#pragma unroll 1
    for (int n = 0; n < nj; ++n)
        s += yp[((size_t)n * 4096 + b) * 128 + f];
    const float scale = gamma[0] * rsqrtf(mvar[0] + 1e-3f);
    float y = (s + fc_b[0] - mmean[0]) * scale + beta[0];

    __shared__ float redm[2], reds[2];
    float m = y;
#pragma unroll
    for (int o = 32; o >= 1; o >>= 1) m = fmaxf(m, __shfl_xor(m, o, 64));
    const int wid = f >> 6;
    if ((f & 63) == 0) redm[wid] = m;
    __syncthreads();
    m = fmaxf(redm[0], redm[1]);
    float e = __expf(y - m);
    float ss = e;
#pragma unroll
    for (int o = 32; o >= 1; o >>= 1) ss += __shfl_xor(ss, o, 64);
    if ((f & 63) == 0) reds[wid] = ss;
    __syncthreads();
    out[(size_t)b * 128 + f] = e / (reds[0] + reds[1]);
}

// ---------------------------------------------------------------------------
extern "C" void kernel_launch(void* const* d_in, const int* in_sizes, int n_in,
                              void* d_out, int out_size, void* d_ws, size_t ws_size,
                              hipStream_t stream) {
    const float* x     = (const float*)d_in[0];
    const float* K     = (const float*)d_in[1];
    const float* fc_w  = (const float*)d_in[2];
    const float* fc_b  = (const float*)d_in[3];
    const float* gamma = (const float*)d_in[4];
    const float* beta  = (const float*)d_in[5];
    const float* mmean = (const float*)d_in[6];
    const float* mvar  = (const float*)d_in[7];
    float* out = (float*)d_out;

    unsigned short* KbT = (unsigned short*)d_ws;            // 4 MB
    unsigned short* W2  = KbT + 2097152;                    // 4 MB
    unsigned short* Kjj = W2 + 2097152;                     // 32 KB
    const size_t tab_bytes = 8421376;
    float* yp = (float*)((char*)d_ws + tab_bytes);

    int nj = (ws_size >= tab_bytes + (size_t)16 * 4096 * 128 * 4) ? 16 : 8;
    int jpc = 128 / nj;

    hipLaunchKernelGGL(ife_prep3, dim3(512),     dim3(256), 0, stream, K, fc_w, KbT, W2, Kjj);
    hipLaunchKernelGGL(ife_main2, dim3(64 * nj), dim3(256), 0, stream, x, KbT, W2, Kjj, yp, jpc);
    hipLaunchKernelGGL(ife_final, dim3(4096),    dim3(128), 0, stream,
                       yp, fc_b, gamma, beta, mmean, mvar, out, nj);
}

// Round 13
// 144.982 us; speedup vs baseline: 1.5616x; 1.0119x over previous
//
#include <hip/hip_runtime.h>
#include <hip/hip_bf16.h>

// B=4096 rows, F=128 features, A=8 heads, U=10 units (padded to 16).
// y = softmax_f( BN( (1/F) sum_{j,a,u} softmax_u(Z[j,a,b,:])[u] exp(2K[j,a,f,u]) fc_w[a] + fc_b ) )
// Z[j,a,b,u] = sum_f x[b,f] K[j,a,f,u] - x[b,j] K[j,a,j,u]
//
// MFMA plan (16x16x32 bf16, fp32 accum):
//   GEMM1 (transposed): Z^T[u][b] = KbT[u][f] * x[f][b]  -> u in-lane for softmax
//   GEMM2: acc[b][f] += P[b][k=(a-pair,u)] * W2[k][f], k=32 packs 2 heads
//
// Measured history: R7 xf-cached: occ 24%, 110us. R8 x-from-LDS: occ 36%, 78us.
// R11 (no-max softmax + cvt_pk + hoist): 68us, VALU 43%, Mfma 20%, VGPR 64.
// R12: merge both heads in GEMM1 (x read ONCE per j, 2 MFMAs per read; all 8
// af loads issued together) + KbT/Kjj pre-scaled by log2(e); softmax uses
// __builtin_amdgcn_exp2f (v_exp_f32 is natively 2^x). R12 compile fix:
// __exp2f does not exist in HIP device code (glibc macro collision) -> builtin.

typedef __attribute__((ext_vector_type(8))) short short8v;
typedef __attribute__((ext_vector_type(4))) float f32x4;

__device__ inline unsigned short f2bf(float f) {
    union { float f; unsigned u; } c; c.f = f;
    return (unsigned short)((c.u + 0x7FFFu + ((c.u >> 16) & 1u)) >> 16);
}
__device__ inline float bf2f(unsigned short h) {
    union { unsigned u; float f; } c; c.u = ((unsigned)h) << 16;
    return c.f;
}
__device__ inline unsigned pack_bf2(float lo, float hi) {
    __hip_bfloat162 h = __float22bfloat162_rn(float2{lo, hi});  // v_cvt_pk_bf16_f32
    union { __hip_bfloat162 h; unsigned u; } c; c.h = h;
    return c.u;
}

// ---------------------------------------------------------------------------
// Prep (coalesced): block = (j, pair p). Computes
//   KbT[j][a][u16][f128] bf16 * log2e  (GEMM1 operand, exp2 domain)
//   W2 [j][p][f128][k32] bf16 (k=ai*16+u) = exp(2K)*fc_w/128
//   Kjj[j][a][u16] bf16 * log2e        (rank-1 correction, same domain)
// ---------------------------------------------------------------------------
__global__ __launch_bounds__(256) void ife_prep3(
    const float* __restrict__ K, const float* __restrict__ fc_w,
    unsigned short* __restrict__ KbT, unsigned short* __restrict__ W2,
    unsigned short* __restrict__ Kjj) {
    const int j = blockIdx.x >> 2, p = blockIdx.x & 3;
    const int t = threadIdx.x;
    const float LOG2E = 1.4426950408889634f;
    __shared__ unsigned short wt[128 * 32];      // [f][k]  8KB
    __shared__ unsigned short kt[2 * 128 * 16];  // [ai][f][u]  8KB
    const int ai = t >> 7, f = t & 127, a = p * 2 + ai;
    const float* src = K + (size_t)((j * 8 + a) * 128 + f) * 10;
    const float wscale = fc_w[a] * (1.0f / 128.0f);
    float kv[10];
#pragma unroll
    for (int u = 0; u < 10; ++u) kv[u] = src[u];
#pragma unroll
    for (int u = 0; u < 16; ++u) {
        unsigned short kb = (u < 10) ? f2bf(kv[u] * LOG2E) : (unsigned short)0;
        kt[(ai * 128 + f) * 16 + u] = kb;
        wt[f * 32 + ai * 16 + u] =
            (u < 10) ? f2bf(__expf(2.0f * kv[u]) * wscale) : (unsigned short)0;
        if (f == j) Kjj[(size_t)(j * 8 + a) * 16 + u] = kb;
    }
    __syncthreads();
    {
        const unsigned* s = (const unsigned*)wt;
        unsigned* d = (unsigned*)(W2 + (size_t)(j * 4 + p) * 128 * 32);
#pragma unroll
        for (int i = 0; i < 8; ++i) d[i * 256 + t] = s[i * 256 + t];
    }
#pragma unroll
    for (int a2 = 0; a2 < 2; ++a2) {
        unsigned* d = (unsigned*)(KbT + (size_t)((j * 8 + p * 2 + a2) * 16) * 128);
#pragma unroll
        for (int i = 0; i < 4; ++i) {
            int dd = i * 256 + t;
            int u = dd >> 6, f2 = (dd & 63) * 2;
            unsigned lo = kt[(a2 * 128 + f2) * 16 + u];
            unsigned hi = kt[(a2 * 128 + f2 + 1) * 16 + u];
            d[dd] = lo | (hi << 16);
        }
    }
}

// ---------------------------------------------------------------------------
// Main: block = 256 threads (4 waves), 64-row b-tile, one j-chunk (jpc j's).
// Wave w: GEMM1+softmax for heads a=2w,2w+1 (both in ONE pass); GEMM2 f-block w*32.
// ---------------------------------------------------------------------------
__global__ __launch_bounds__(256, 2) void ife_main2(
    const float* __restrict__ x, const unsigned short* __restrict__ KbT,
    const unsigned short* __restrict__ W2, const unsigned short* __restrict__ Kjj,
    float* __restrict__ yp, int jpc) {
    __shared__ unsigned xb[64 * 64];    // x tile bf16x2, f-octet XOR-swizzled (16KB)
    __shared__ unsigned pb[4 * 64 * 16];// P bf16x2 [pair][b][k-dword], swizzled (16KB)

    const int t = threadIdx.x;
    const int btile = blockIdx.x & 63;
    const int chunk = blockIdx.x >> 6;
    const int b0 = btile * 64;
    const int lane = t & 63;
    const int wv = __builtin_amdgcn_readfirstlane(t >> 6);
    const int lr = lane & 15;   // row/col within a 16-tile
    const int lg = lane >> 4;   // k-octet group (0..3)
    const int bx = lr & 7;      // swizzle key for rows lr, lr+16, ...

    // stage x -> bf16 LDS: dword dw holds f=2dw,2dw+1; octet g stored at g^(b&7)
    for (int i = t; i < 64 * 64; i += 256) {
        int b = i >> 6, dw = i & 63;
        float2 v = *reinterpret_cast<const float2*>(x + (size_t)(b0 + b) * 128 + dw * 2);
        unsigned pk = pack_bf2(v.x, v.y);
        int g = dw >> 2;
        xb[b * 64 + (((g ^ (b & 7)) << 2) | (dw & 3))] = pk;
    }
    __syncthreads();

    f32x4 acc[4][2];
#pragma unroll
    for (int mt = 0; mt < 4; ++mt)
#pragma unroll
        for (int nt = 0; nt < 2; ++nt) acc[mt][nt] = f32x4{0.f, 0.f, 0.f, 0.f};

    const int ub = lg * 4;      // this lane's base u (GEMM1 D rows)

#pragma unroll 1
    for (int jj = 0; jj < jpc; ++jj) {
        const int j = chunk * jpc + jj;
        // rank-1 x[b,j] values: head-invariant, hoisted
        const int gj = j >> 3;
        float xbj[4];
#pragma unroll
        for (int nt = 0; nt < 4; ++nt) {
            int b = nt * 16 + lr;
            unsigned pkx = xb[b * 64 + (((gj ^ (b & 7)) << 2) | ((j >> 1) & 3))];
            xbj[nt] = bf2f((unsigned short)((j & 1) ? (pkx >> 16) : (pkx & 0xFFFFu)));
        }
        // ---- GEMM1, BOTH heads in one pass (x read once, 2 MFMAs per read) ----
        const size_t kbase = (size_t)(j * 8 + wv * 2) * 16;   // head ai=0; ai=1 at +16
        short8v af[2][4];
#pragma unroll
        for (int ks = 0; ks < 4; ++ks) {
            af[0][ks] = *reinterpret_cast<const short8v*>(
                KbT + (kbase + lr) * 128 + ks * 32 + lg * 8);
            af[1][ks] = *reinterpret_cast<const short8v*>(
                KbT + (kbase + 16 + lr) * 128 + ks * 32 + lg * 8);
        }
        f32x4 z[2][4];
#pragma unroll
        for (int ai = 0; ai < 2; ++ai)
#pragma unroll
            for (int nt = 0; nt < 4; ++nt) z[ai][nt] = f32x4{0.f, 0.f, 0.f, 0.f};
#pragma unroll
        for (int ks = 0; ks < 4; ++ks) {
            const int xoff = ((ks * 4 + lg) ^ bx) << 2;
#pragma unroll
            for (int nt = 0; nt < 4; ++nt) {
                short8v xv = *reinterpret_cast<const short8v*>(
                    &xb[(nt * 16 + lr) * 64 + xoff]);
                z[0][nt] = __builtin_amdgcn_mfma_f32_16x16x32_bf16(
                    af[0][ks], xv, z[0][nt], 0, 0, 0);
                z[1][nt] = __builtin_amdgcn_mfma_f32_16x16x32_bf16(
                    af[1][ks], xv, z[1][nt], 0, 0, 0);
            }
        }
        // rank-1 correction, both heads (all values in log2e-scaled domain)
        unsigned short kj[2][4];
#pragma unroll
        for (int ai = 0; ai < 2; ++ai) {
            const unsigned short* kp = Kjj + kbase + ai * 16 + ub;
            kj[ai][0] = kp[0]; kj[ai][1] = kp[1]; kj[ai][2] = kp[2]; kj[ai][3] = kp[3];
        }
#pragma unroll
        for (int ai = 0; ai < 2; ++ai)
#pragma unroll
            for (int nt = 0; nt < 4; ++nt) {
                z[ai][nt][0] = fmaf(-bf2f(kj[ai][0]), xbj[nt], z[ai][nt][0]);
                z[ai][nt][1] = fmaf(-bf2f(kj[ai][1]), xbj[nt], z[ai][nt][1]);
                z[ai][nt][2] = fmaf(-bf2f(kj[ai][2]), xbj[nt], z[ai][nt][2]);
                z[ai][nt][3] = fmaf(-bf2f(kj[ai][3]), xbj[nt], z[ai][nt][3]);
            }
        // softmax over u, no max-subtract (|z'| <~ 15 << 126, exp2 safe);
        // z is in log2 domain -> v_exp_f32 (2^x) via builtin.
#pragma unroll
        for (int ai = 0; ai < 2; ++ai)
#pragma unroll
            for (int nt = 0; nt < 4; ++nt) {
                float e0 = (ub + 0 < 10) ? __builtin_amdgcn_exp2f(z[ai][nt][0]) : 0.f;
                float e1 = (ub + 1 < 10) ? __builtin_amdgcn_exp2f(z[ai][nt][1]) : 0.f;
                float e2 = (ub + 2 < 10) ? __builtin_amdgcn_exp2f(z[ai][nt][2]) : 0.f;
                float e3 = (ub + 3 < 10) ? __builtin_amdgcn_exp2f(z[ai][nt][3]) : 0.f;
                float s = e0 + e1 + e2 + e3;
                s += __shfl_xor(s, 16, 64);
                s += __shfl_xor(s, 32, 64);
                float inv = 1.0f / s;
                int b = nt * 16 + lr;
                unsigned pk0 = pack_bf2(e0 * inv, e1 * inv);
                unsigned pk1 = pack_bf2(e2 * inv, e3 * inv);
                int dw0 = ai * 8 + lg * 2;           // k-dword col (k = ai*16 + u)
                int base = (wv * 64 + b) * 16;
                int swz = (b >> 1) & 3;
                pb[base + ((((dw0 >> 2) ^ swz) << 2) | (dw0 & 3))] = pk0;
                pb[base + ((((dw0 + 1) >> 2) ^ swz) << 2) + ((dw0 + 1) & 3)] = pk1;
            }
        __syncthreads();
        // ---------- GEMM2: acc[b][f-block wv*32] += P * W2 ----------
#pragma unroll
        for (int p = 0; p < 4; ++p) {
            short8v wf[2];   // B-frag: col f = wv*32+nt*16+lr, k = lg*8..+8
#pragma unroll
            for (int nt = 0; nt < 2; ++nt) {
                int f = wv * 32 + nt * 16 + lr;
                wf[nt] = *reinterpret_cast<const short8v*>(
                    W2 + (((size_t)(j * 4 + p) * 128 + f) * 32) + lg * 8);
            }
#pragma unroll
            for (int mt = 0; mt < 4; ++mt) {
                int b = mt * 16 + lr;
                short8v pf = *reinterpret_cast<const short8v*>(
                    &pb[(p * 64 + b) * 16 + ((lg ^ ((b >> 1) & 3)) << 2)]);
#pragma unroll
                for (int nt = 0; nt < 2; ++nt)
                    acc[mt][nt] = __builtin_amdgcn_mfma_f32_16x16x32_bf16(
                        pf, wf[nt], acc[mt][nt], 0, 0, 0);
            }
        }
        __syncthreads();
    }
    // store partials: D layout col=lr (f), row=lg*4+q (b)
    float* ypb = yp + ((size_t)chunk * 4096 + b0) * 128;
#pragma unroll
    for (int mt = 0; mt < 4; ++mt)
#pragma unroll
        for (int nt = 0; nt < 2; ++nt) {
            int f = wv * 32 + nt * 16 + lr;
#pragma unroll
            for (int q = 0; q < 4; ++q) {
                int b = mt * 16 + lg * 4 + q;
                ypb[(size_t)b * 128 + f] = acc[mt][nt][q];
            }
        }
}

// ---------------------------------------------------------------------------
// Finalize: sum nj partials, + fc_b, inference BN, row-softmax over F=128.
// ---------------------------------------------------------------------------
__global__ void ife_final(const float* __restrict__ yp, const float* __restrict__ fc_b,
                          const float* __restrict__ gamma, const float* __restrict__ beta,
                          const float* __restrict__ mmean, const float* __restrict__ mvar,
                          float* __restrict__ out, int nj) {
    const int b = blockIdx.x;
    const int f = threadIdx.x;  // 128
    float s = 0.f;
#pragma unroll 1
    for (int n = 0; n < nj; ++n)
        s += yp[((size_t)n * 4096 + b) * 128 + f];
    const float scale = gamma[0] * rsqrtf(mvar[0] + 1e-3f);
    float y = (s + fc_b[0] - mmean[0]) * scale + beta[0];

    __shared__ float redm[2], reds[2];
    float m = y;
#pragma unroll
    for (int o = 32; o >= 1; o >>= 1) m = fmaxf(m, __shfl_xor(m, o, 64));
    const int wid = f >> 6;
    if ((f & 63) == 0) redm[wid] = m;
    __syncthreads();
    m = fmaxf(redm[0], redm[1]);
    float e = __expf(y - m);
    float ss = e;
#pragma unroll
    for (int o = 32; o >= 1; o >>= 1) ss += __shfl_xor(ss, o, 64);
    if ((f & 63) == 0) reds[wid] = ss;
    __syncthreads();
    out[(size_t)b * 128 + f] = e / (reds[0] + reds[1]);
}

// ---------------------------------------------------------------------------
extern "C" void kernel_launch(void* const* d_in, const int* in_sizes, int n_in,
                              void* d_out, int out_size, void* d_ws, size_t ws_size,
                              hipStream_t stream) {
    const float* x     = (const float*)d_in[0];
    const float* K     = (const float*)d_in[1];
    const float* fc_w  = (const float*)d_in[2];
    const float* fc_b  = (const float*)d_in[3];
    const float* gamma = (const float*)d_in[4];
    const float* beta  = (const float*)d_in[5];
    const float* mmean = (const float*)d_in[6];
    const float* mvar  = (const float*)d_in[7];
    float* out = (float*)d_out;

    unsigned short* KbT = (unsigned short*)d_ws;            // 4 MB
    unsigned short* W2  = KbT + 2097152;                    // 4 MB
    unsigned short* Kjj = W2 + 2097152;                     // 32 KB
    const size_t tab_bytes = 8421376;
    float* yp = (float*)((char*)d_ws + tab_bytes);

    int nj = (ws_size >= tab_bytes + (size_t)16 * 4096 * 128 * 4) ? 16 : 8;
    int jpc = 128 / nj;

    hipLaunchKernelGGL(ife_prep3, dim3(512),     dim3(256), 0, stream, K, fc_w, KbT, W2, Kjj);
    hipLaunchKernelGGL(ife_main2, dim3(64 * nj), dim3(256), 0, stream, x, KbT, W2, Kjj, yp, jpc);
    hipLaunchKernelGGL(ife_final, dim3(4096),    dim3(128), 0, stream,
                       yp, fc_b, gamma, beta, mmean, mvar, out, nj);
}

// Round 14
// 144.715 us; speedup vs baseline: 1.5645x; 1.0018x over previous
//
#include <hip/hip_runtime.h>
#include <hip/hip_bf16.h>

// B=4096 rows, F=128 features, A=8 heads, U=10 units (padded to 16).
// y = softmax_f( BN( (1/F) sum_{j,a,u} softmax_u(Z[j,a,b,:])[u] exp(2K[j,a,f,u]) fc_w[a] + fc_b ) )
// Z[j,a,b,u] = sum_f x[b,f] K[j,a,f,u] - x[b,j] K[j,a,j,u]
//
// MFMA plan (16x16x32 bf16, fp32 accum):
//   GEMM1 (transposed): Z^T[u][b] = KbT[u][f] * x[f][b]  -> u in-lane for softmax
//   GEMM2: acc[b][f] += P[b][k=(a-pair,u)] * W2[k][f], k=32 packs 2 heads
//
// Measured history: R8 x-from-LDS: 78us. R11 (softmax VALU cut): 68us,
// VALU 43%, Mfma 20%. R13 (merged-head GEMM1 + exp2): 70.8us, VALU 39%,
// stall ~42% -> latency-bound, not VALU-bound.
// R14: T14 issue-early prefetch -- ALL 8 wf (W2) fragments for iteration j
// loaded at the TOP of the j-loop (with af), consumed after barrier1. W2 has
// zero intra-block reuse so register prefetch (not LDS) is correct. ~150
// unified regs -> stays 3 waves/SIMD (occupancy-neutral).

typedef __attribute__((ext_vector_type(8))) short short8v;
typedef __attribute__((ext_vector_type(4))) float f32x4;

__device__ inline unsigned short f2bf(float f) {
    union { float f; unsigned u; } c; c.f = f;
    return (unsigned short)((c.u + 0x7FFFu + ((c.u >> 16) & 1u)) >> 16);
}
__device__ inline float bf2f(unsigned short h) {
    union { unsigned u; float f; } c; c.u = ((unsigned)h) << 16;
    return c.f;
}
__device__ inline unsigned pack_bf2(float lo, float hi) {
    __hip_bfloat162 h = __float22bfloat162_rn(float2{lo, hi});  // v_cvt_pk_bf16_f32
    union { __hip_bfloat162 h; unsigned u; } c; c.h = h;
    return c.u;
}

// ---------------------------------------------------------------------------
// Prep (coalesced): block = (j, pair p). Computes
//   KbT[j][a][u16][f128] bf16 * log2e  (GEMM1 operand, exp2 domain)
//   W2 [j][p][f128][k32] bf16 (k=ai*16+u) = exp(2K)*fc_w/128
//   Kjj[j][a][u16] bf16 * log2e        (rank-1 correction, same domain)
// ---------------------------------------------------------------------------
__global__ __launch_bounds__(256) void ife_prep3(
    const float* __restrict__ K, const float* __restrict__ fc_w,
    unsigned short* __restrict__ KbT, unsigned short* __restrict__ W2,
    unsigned short* __restrict__ Kjj) {
    const int j = blockIdx.x >> 2, p = blockIdx.x & 3;
    const int t = threadIdx.x;
    const float LOG2E = 1.4426950408889634f;
    __shared__ unsigned short wt[128 * 32];      // [f][k]  8KB
    __shared__ unsigned short kt[2 * 128 * 16];  // [ai][f][u]  8KB
    const int ai = t >> 7, f = t & 127, a = p * 2 + ai;
    const float* src = K + (size_t)((j * 8 + a) * 128 + f) * 10;
    const float wscale = fc_w[a] * (1.0f / 128.0f);
    float kv[10];
#pragma unroll
    for (int u = 0; u < 10; ++u) kv[u] = src[u];
#pragma unroll
    for (int u = 0; u < 16; ++u) {
        unsigned short kb = (u < 10) ? f2bf(kv[u] * LOG2E) : (unsigned short)0;
        kt[(ai * 128 + f) * 16 + u] = kb;
        wt[f * 32 + ai * 16 + u] =
            (u < 10) ? f2bf(__expf(2.0f * kv[u]) * wscale) : (unsigned short)0;
        if (f == j) Kjj[(size_t)(j * 8 + a) * 16 + u] = kb;
    }
    __syncthreads();
    {
        const unsigned* s = (const unsigned*)wt;
        unsigned* d = (unsigned*)(W2 + (size_t)(j * 4 + p) * 128 * 32);
#pragma unroll
        for (int i = 0; i < 8; ++i) d[i * 256 + t] = s[i * 256 + t];
    }
#pragma unroll
    for (int a2 = 0; a2 < 2; ++a2) {
        unsigned* d = (unsigned*)(KbT + (size_t)((j * 8 + p * 2 + a2) * 16) * 128);
#pragma unroll
        for (int i = 0; i < 4; ++i) {
            int dd = i * 256 + t;
            int u = dd >> 6, f2 = (dd & 63) * 2;
            unsigned lo = kt[(a2 * 128 + f2) * 16 + u];
            unsigned hi = kt[(a2 * 128 + f2 + 1) * 16 + u];
            d[dd] = lo | (hi << 16);
        }
    }
}

// ---------------------------------------------------------------------------
// Main: block = 256 threads (4 waves), 64-row b-tile, one j-chunk (jpc j's).
// Wave w: GEMM1+softmax for heads a=2w,2w+1 (one pass); GEMM2 f-block w*32.
// Per j: issue af+wf loads FIRST, then GEMM1/softmax (hides wf L2 latency),
// barrier, GEMM2 consumes prefetched wf.
// ---------------------------------------------------------------------------
__global__ __launch_bounds__(256, 2) void ife_main2(
    const float* __restrict__ x, const unsigned short* __restrict__ KbT,
    const unsigned short* __restrict__ W2, const unsigned short* __restrict__ Kjj,
    float* __restrict__ yp, int jpc) {
    __shared__ unsigned xb[64 * 64];    // x tile bf16x2, f-octet XOR-swizzled (16KB)
    __shared__ unsigned pb[4 * 64 * 16];// P bf16x2 [pair][b][k-dword], swizzled (16KB)

    const int t = threadIdx.x;
    const int btile = blockIdx.x & 63;
    const int chunk = blockIdx.x >> 6;
    const int b0 = btile * 64;
    const int lane = t & 63;
    const int wv = __builtin_amdgcn_readfirstlane(t >> 6);
    const int lr = lane & 15;   // row/col within a 16-tile
    const int lg = lane >> 4;   // k-octet group (0..3)
    const int bx = lr & 7;      // swizzle key for rows lr, lr+16, ...

    // stage x -> bf16 LDS: dword dw holds f=2dw,2dw+1; octet g stored at g^(b&7)
    for (int i = t; i < 64 * 64; i += 256) {
        int b = i >> 6, dw = i & 63;
        float2 v = *reinterpret_cast<const float2*>(x + (size_t)(b0 + b) * 128 + dw * 2);
        unsigned pk = pack_bf2(v.x, v.y);
        int g = dw >> 2;
        xb[b * 64 + (((g ^ (b & 7)) << 2) | (dw & 3))] = pk;
    }
    __syncthreads();

    f32x4 acc[4][2];
#pragma unroll
    for (int mt = 0; mt < 4; ++mt)
#pragma unroll
        for (int nt = 0; nt < 2; ++nt) acc[mt][nt] = f32x4{0.f, 0.f, 0.f, 0.f};

    const int ub = lg * 4;      // this lane's base u (GEMM1 D rows)

#pragma unroll 1
    for (int jj = 0; jj < jpc; ++jj) {
        const int j = chunk * jpc + jj;
        // ---- ISSUE-EARLY: all global loads for this j, back-to-back ----
        const size_t kbase = (size_t)(j * 8 + wv * 2) * 16;   // head ai=0; ai=1 at +16
        short8v af[2][4];
#pragma unroll
        for (int ks = 0; ks < 4; ++ks) {
            af[0][ks] = *reinterpret_cast<const short8v*>(
                KbT + (kbase + lr) * 128 + ks * 32 + lg * 8);
            af[1][ks] = *reinterpret_cast<const short8v*>(
                KbT + (kbase + 16 + lr) * 128 + ks * 32 + lg * 8);
        }
        short8v wf[4][2];   // GEMM2 B-frags, consumed after barrier1 (T14)
#pragma unroll
        for (int p = 0; p < 4; ++p)
#pragma unroll
            for (int nt = 0; nt < 2; ++nt) {
                int f = wv * 32 + nt * 16 + lr;
                wf[p][nt] = *reinterpret_cast<const short8v*>(
                    W2 + (((size_t)(j * 4 + p) * 128 + f) * 32) + lg * 8);
            }
        // rank-1 x[b,j] values: head-invariant
        const int gj = j >> 3;
        float xbj[4];
#pragma unroll
        for (int nt = 0; nt < 4; ++nt) {
            int b = nt * 16 + lr;
            unsigned pkx = xb[b * 64 + (((gj ^ (b & 7)) << 2) | ((j >> 1) & 3))];
            xbj[nt] = bf2f((unsigned short)((j & 1) ? (pkx >> 16) : (pkx & 0xFFFFu)));
        }
        // ---- GEMM1, both heads in one pass (x read once, 2 MFMAs per read) ----
        f32x4 z[2][4];
#pragma unroll
        for (int ai = 0; ai < 2; ++ai)
#pragma unroll
            for (int nt = 0; nt < 4; ++nt) z[ai][nt] = f32x4{0.f, 0.f, 0.f, 0.f};
#pragma unroll
        for (int ks = 0; ks < 4; ++ks) {
            const int xoff = ((ks * 4 + lg) ^ bx) << 2;
#pragma unroll
            for (int nt = 0; nt < 4; ++nt) {
                short8v xv = *reinterpret_cast<const short8v*>(
                    &xb[(nt * 16 + lr) * 64 + xoff]);
                z[0][nt] = __builtin_amdgcn_mfma_f32_16x16x32_bf16(
                    af[0][ks], xv, z[0][nt], 0, 0, 0);
                z[1][nt] = __builtin_amdgcn_mfma_f32_16x16x32_bf16(
                    af[1][ks], xv, z[1][nt], 0, 0, 0);
            }
        }
        // rank-1 correction, both heads (log2e-scaled domain)
        unsigned short kj[2][4];
#pragma unroll
        for (int ai = 0; ai < 2; ++ai) {
            const unsigned short* kp = Kjj + kbase + ai * 16 + ub;
            kj[ai][0] = kp[0]; kj[ai][1] = kp[1]; kj[ai][2] = kp[2]; kj[ai][3] = kp[3];
        }
#pragma unroll
        for (int ai = 0; ai < 2; ++ai)
#pragma unroll
            for (int nt = 0; nt < 4; ++nt) {
                z[ai][nt][0] = fmaf(-bf2f(kj[ai][0]), xbj[nt], z[ai][nt][0]);
                z[ai][nt][1] = fmaf(-bf2f(kj[ai][1]), xbj[nt], z[ai][nt][1]);
                z[ai][nt][2] = fmaf(-bf2f(kj[ai][2]), xbj[nt], z[ai][nt][2]);
                z[ai][nt][3] = fmaf(-bf2f(kj[ai][3]), xbj[nt], z[ai][nt][3]);
            }
        // softmax over u, no max-subtract; log2 domain -> v_exp_f32 (2^x)
#pragma unroll
        for (int ai = 0; ai < 2; ++ai)
#pragma unroll
            for (int nt = 0; nt < 4; ++nt) {
                float e0 = (ub + 0 < 10) ? __builtin_amdgcn_exp2f(z[ai][nt][0]) : 0.f;
                float e1 = (ub + 1 < 10) ? __builtin_amdgcn_exp2f(z[ai][nt][1]) : 0.f;
                float e2 = (ub + 2 < 10) ? __builtin_amdgcn_exp2f(z[ai][nt][2]) : 0.f;
                float e3 = (ub + 3 < 10) ? __builtin_amdgcn_exp2f(z[ai][nt][3]) : 0.f;
                float s = e0 + e1 + e2 + e3;
                s += __shfl_xor(s, 16, 64);
                s += __shfl_xor(s, 32, 64);
                float inv = 1.0f / s;
                int b = nt * 16 + lr;
                unsigned pk0 = pack_bf2(e0 * inv, e1 * inv);
                unsigned pk1 = pack_bf2(e2 * inv, e3 * inv);
                int dw0 = ai * 8 + lg * 2;           // k-dword col (k = ai*16 + u)
                int base = (wv * 64 + b) * 16;
                int swz = (b >> 1) & 3;
                pb[base + ((((dw0 >> 2) ^ swz) << 2) | (dw0 & 3))] = pk0;
                pb[base + ((((dw0 + 1) >> 2) ^ swz) << 2) + ((dw0 + 1) & 3)] = pk1;
            }
        __syncthreads();
        // ---------- GEMM2: acc[b][f-block wv*32] += P * W2 (wf prefetched) ----------
#pragma unroll
        for (int p = 0; p < 4; ++p) {
#pragma unroll
            for (int mt = 0; mt < 4; ++mt) {
                int b = mt * 16 + lr;
                short8v pf = *reinterpret_cast<const short8v*>(
                    &pb[(p * 64 + b) * 16 + ((lg ^ ((b >> 1) & 3)) << 2)]);
#pragma unroll
                for (int nt = 0; nt < 2; ++nt)
                    acc[mt][nt] = __builtin_amdgcn_mfma_f32_16x16x32_bf16(
                        pf, wf[p][nt], acc[mt][nt], 0, 0, 0);
            }
        }
        __syncthreads();
    }
    // store partials: D layout col=lr (f), row=lg*4+q (b)
    float* ypb = yp + ((size_t)chunk * 4096 + b0) * 128;
#pragma unroll
    for (int mt = 0; mt < 4; ++mt)
#pragma unroll
        for (int nt = 0; nt < 2; ++nt) {
            int f = wv * 32 + nt * 16 + lr;
#pragma unroll
            for (int q = 0; q < 4; ++q) {
                int b = mt * 16 + lg * 4 + q;
                ypb[(size_t)b * 128 + f] = acc[mt][nt][q];
            }
        }
}

// ---------------------------------------------------------------------------
// Finalize: sum nj partials, + fc_b, inference BN, row-softmax over F=128.
// ---------------------------------------------------------------------------
__global__ void ife_final(const float* __restrict__ yp, const float* __restrict__ fc_b,
                          const float* __restrict__ gamma, const float* __restrict__ beta,
                          const float* __restrict__ mmean, const float* __restrict__ mvar,
                          float* __restrict__ out, int nj) {
    const int b = blockIdx.x;
    const int f = threadIdx.x;  // 128
    float s = 0.f;
#pragma unroll 1
    for (int n = 0; n < nj; ++n)
        s += yp[((size_t)n * 4096 + b) * 128 + f];
    const float scale = gamma[0] * rsqrtf(mvar[0] + 1e-3f);
    float y = (s + fc_b[0] - mmean[0]) * scale + beta[0];

    __shared__ float redm[2], reds[2];
    float m = y;
#pragma unroll
    for (int o = 32; o >= 1; o >>= 1) m = fmaxf(m, __shfl_xor(m, o, 64));
    const int wid = f >> 6;
    if ((f & 63) == 0) redm[wid] = m;
    __syncthreads();
    m = fmaxf(redm[0], redm[1]);
    float e = __expf(y - m);
    float ss = e;
#pragma unroll
    for (int o = 32; o >= 1; o >>= 1) ss += __shfl_xor(ss, o, 64);
    if ((f & 63) == 0) reds[wid] = ss;
    __syncthreads();
    out[(size_t)b * 128 + f] = e / (reds[0] + reds[1]);
}

// ---------------------------------------------------------------------------
extern "C" void kernel_launch(void* const* d_in, const int* in_sizes, int n_in,
                              void* d_out, int out_size, void* d_ws, size_t ws_size,
                              hipStream_t stream) {
    const float* x     = (const float*)d_in[0];
    const float* K     = (const float*)d_in[1];
    const float* fc_w  = (const float*)d_in[2];
    const float* fc_b  = (const float*)d_in[3];
    const float* gamma = (const float*)d_in[4];
    const float* beta  = (const float*)d_in[5];
    const float* mmean = (const float*)d_in[6];
    const float* mvar  = (const float*)d_in[7];
    float* out = (float*)d_out;

    unsigned short* KbT = (unsigned short*)d_ws;            // 4 MB
    unsigned short* W2  = KbT + 2097152;                    // 4 MB
    unsigned short* Kjj = W2 + 2097152;                     // 32 KB
    const size_t tab_bytes = 8421376;
    float* yp = (float*)((char*)d_ws + tab_bytes);

    int nj = (ws_size >= tab_bytes + (size_t)16 * 4096 * 128 * 4) ? 16 : 8;
    int jpc = 128 / nj;

    hipLaunchKernelGGL(ife_prep3, dim3(512),     dim3(256), 0, stream, K, fc_w, KbT, W2, Kjj);
    hipLaunchKernelGGL(ife_main2, dim3(64 * nj), dim3(256), 0, stream, x, KbT, W2, Kjj, yp, jpc);
    hipLaunchKernelGGL(ife_final, dim3(4096),    dim3(128), 0, stream,
                       yp, fc_b, gamma, beta, mmean, mvar, out, nj);
}